// Round 14
// baseline (279.726 us; speedup 1.0000x reference)
//
#include <hip/hip_runtime.h>

#define N_IMG 4
#define C_CH  256
#define FH    100
#define FW    152
#define CHW   (C_CH * FH * FW)
#define OUT_PER_ROI (C_CH * 7 * 7)   // 12544
#define SCALE 0.0625f
#define H_ROW_BYTES (FW * C_CH * 2)  // 77824  (f16 NHWC feature row)
#define H_CH_BYTES  (C_CH * 2)       // 512    (one (y,x) cell, f16)
#define CPH 260                      // f16 LDS row stride (elements) — MUST be >= C_CH=256.
                                     // 520 B rows (8-B aligned); 56*260*2 = 29,120 B LDS.

typedef float    f4 __attribute__((ext_vector_type(4)));
typedef _Float16 h4 __attribute__((ext_vector_type(4)));

// ---------------- Kernel 0: bucket ROIs by (image, 8x8 spatial cell) ----------
__global__ __launch_bounds__(256) void bin_rois(
    const float* __restrict__ rois, const int* __restrict__ bids, int R,
    int* __restrict__ order) {
  __shared__ int hist[256];
  __shared__ int base[256];
  for (int k = threadIdx.x; k < 256; k += 256) hist[k] = 0;
  __syncthreads();
  for (int r = threadIdx.x; r < R; r += 256) {
    const float cx = (rois[r * 4 + 0] + rois[r * 4 + 2]) * 0.5f * SCALE;
    const float cy = (rois[r * 4 + 1] + rois[r * 4 + 3]) * 0.5f * SCALE;
    int xb = (int)(cx * (8.0f / FW)); xb = xb < 0 ? 0 : (xb > 7 ? 7 : xb);
    int yb = (int)(cy * (8.0f / FH)); yb = yb < 0 ? 0 : (yb > 7 ? 7 : yb);
    const int key = (bids[r] << 6) | (yb << 3) | xb;
    atomicAdd(&hist[key], 1);
  }
  __syncthreads();
  if (threadIdx.x == 0) {
    int s = 0;
    for (int k = 0; k < 256; ++k) { base[k] = s; s += hist[k]; }
  }
  __syncthreads();
  for (int r = threadIdx.x; r < R; r += 256) {
    const float cx = (rois[r * 4 + 0] + rois[r * 4 + 2]) * 0.5f * SCALE;
    const float cy = (rois[r * 4 + 1] + rois[r * 4 + 3]) * 0.5f * SCALE;
    int xb = (int)(cx * (8.0f / FW)); xb = xb < 0 ? 0 : (xb > 7 ? 7 : xb);
    int yb = (int)(cy * (8.0f / FH)); yb = yb < 0 ? 0 : (yb > 7 ? 7 : yb);
    const int key = (bids[r] << 6) | (yb << 3) | xb;
    const int pos = atomicAdd(&base[key], 1);
    order[pos] = r;
  }
}

// ---------------- Kernel 1: NCHW f32 -> NHWC f16 transpose of features -------
__global__ __launch_bounds__(256) void transpose_nchw_nhwc(
    const float* __restrict__ in, _Float16* __restrict__ out) {
  const int x0 = blockIdx.x * 32;
  const int y  = blockIdx.y;
  const int b  = blockIdx.z;
  __shared__ float tile[32][C_CH + 4];
  const int chl = threadIdx.x & 31;
  const int xq  = threadIdx.x >> 5;
  const int x   = x0 + xq * 4;
  const bool inb = (x < FW);
  const float4* src4 = (const float4*)in;
#pragma unroll
  for (int cc = 0; cc < C_CH; cc += 32) {
    const int ch = cc + chl;
    float4 v = make_float4(0.f, 0.f, 0.f, 0.f);
    if (inb) v = src4[((size_t)b * C_CH + ch) * (FH * FW / 4) + y * (FW / 4) + (x >> 2)];
    tile[xq * 4 + 0][ch] = v.x;
    tile[xq * 4 + 1][ch] = v.y;
    tile[xq * 4 + 2][ch] = v.z;
    tile[xq * 4 + 3][ch] = v.w;
  }
  __syncthreads();
  const int chg = threadIdx.x & 63;
  const int xs  = threadIdx.x >> 6;
  _Float16* dstB = out + (((size_t)b * FH + y) * FW) * C_CH;
#pragma unroll
  for (int xi = 0; xi < 32; xi += 4) {
    const int xx = x0 + xi + xs;
    if (xx < FW) {
      const f4 v = *(const f4*)&tile[xi + xs][chg * 4];
      h4 hv;
      hv[0] = (_Float16)v[0]; hv[1] = (_Float16)v[1];
      hv[2] = (_Float16)v[2]; hv[3] = (_Float16)v[3];
      *(h4*)(dstB + (size_t)xx * C_CH + chg * 4) = hv;
    }
  }
}

// ---------------- Kernel 2: RoIAlign + 2x2 avg pool, f16-hp staged ----------
// 512 threads, one block per ROI. Wave i gathers sample row i (32 h4 loads in
// flight), bilinear in f32, stages HORIZONTAL pair-sums hp[i][j] as f16 in
// LDS [56][CPH] (29.1 KB). Phase 2: out = (hp[rr] + hp[rr+7]) * 0.25.
// __launch_bounds__(512,8) -> 4 blocks/CU, 32 waves/CU (chip max; was 24).
// VGPR cap 64: phase-1 live state ~50-60 VGPR, compiler throttles load
// hoisting rather than spilling. LDS 4*29,120 = 116,480 <= 160 KB.
__global__ __launch_bounds__(512, 8) void roialign_nhwc(
    const _Float16* __restrict__ feat, const float* __restrict__ rois,
    const int* __restrict__ bids, const int* __restrict__ order,
    int R, float* __restrict__ out) {
  const int g  = blockIdx.x;
  const int r  = order[((R & 7) == 0) ? ((g & 7) * (R >> 3) + (g >> 3)) : g];
  const int cg = threadIdx.x & 63;       // channel group: channels 4*cg..4*cg+3
  const int i  = threadIdx.x >> 6;       // sample row 0..7 (wave-uniform)
  __shared__ _Float16 smp[56 * CPH];     // 29,120 B

  const float x1 = rois[r * 4 + 0] * SCALE;
  const float y1 = rois[r * 4 + 1] * SCALE;
  const float x2 = rois[r * 4 + 2] * SCALE;
  const float y2 = rois[r * 4 + 3] * SCALE;
  const int   b  = bids[r];
  const float bw = fmaxf(x2 - x1 + 1.0f, 0.0f) * (1.0f / 7.0f);
  const float bh = fmaxf(y2 - y1 + 1.0f, 0.0f) * (1.0f / 7.0f);

  // Row weights (wave-uniform).
  const float h   = y1 + (float)i * bh;
  const float hsf = fminf(fmaxf(floorf(h), 0.0f), (float)(FH - 2));
  const float hr  = h - hsf;
  const float mh  = (h >= 0.0f && h < (float)FH) ? 1.0f : 0.0f;
  const float a0  = (1.0f - hr) * mh;
  const float a1  = hr * mh;

  const char* fbb  = (const char*)feat + (size_t)b * CHW * 2;
  const int   row0 = (int)hsf * H_ROW_BYTES + cg * 8;

  _Float16* lbase = &smp[(i * 7) * CPH + cg * 4];   // byte off = i*3640 + cg*8: 8-B aligned

  f4 prev;
#pragma unroll
  for (int j = 0; j < 8; ++j) {
    const float w   = x1 + (float)j * bw;
    const float wsf = fminf(fmaxf(floorf(w), 0.0f), (float)(FW - 2));
    const float wr  = w - wsf;
    const float mw  = (w >= 0.0f && w < (float)FW) ? 1.0f : 0.0f;
    const float q0  = (1.0f - wr) * mw;
    const float q1  = wr * mw;
    const int   o0  = row0 + (int)wsf * H_CH_BYTES;
    const h4 h00 = *(const h4*)(fbb + o0);
    const h4 h01 = *(const h4*)(fbb + o0 + H_CH_BYTES);
    const h4 h10 = *(const h4*)(fbb + o0 + H_ROW_BYTES);
    const h4 h11 = *(const h4*)(fbb + o0 + H_ROW_BYTES + H_CH_BYTES);
    const f4 g00 = __builtin_convertvector(h00, f4);
    const f4 g01 = __builtin_convertvector(h01, f4);
    const f4 g10 = __builtin_convertvector(h10, f4);
    const f4 g11 = __builtin_convertvector(h11, f4);
    const f4 s = (g00 * q0 + g01 * q1) * a0 +
                 (g10 * q0 + g11 * q1) * a1;
    if (j > 0) {
      const f4 hp = prev + s;                       // hp[i][j-1]
      h4 hh;
      hh[0] = (_Float16)hp[0]; hh[1] = (_Float16)hp[1];
      hh[2] = (_Float16)hp[2]; hh[3] = (_Float16)hp[3];
      *(h4*)(lbase + (j - 1) * CPH) = hh;
    }
    prev = s;
  }

  __syncthreads();

  // Phase 2: pooled writeback, output-linear (coalesced float4 NT stores).
  // Output element g = c*49 + rr, rr = p*7 + j; hp pair at LDS rows rr, rr+7.
  f4* dst = (f4*)(out + (size_t)r * OUT_PER_ROI);
  const int g0 = (int)threadIdx.x * 4;
  int c   = (g0 * 669) >> 15;          // exact g/49 for g < 2048
  int rem = g0 - c * 49;
#pragma unroll
  for (int k = 0; k < 7; ++k) {
    const int idx = (int)threadIdx.x + k * 512;
    if (idx < (OUT_PER_ROI / 4)) {
      f4 v;
      int cc = c, rr = rem;
#pragma unroll
      for (int e = 0; e < 4; ++e) {
        const int base = rr * CPH + cc;
        v[e] = ((float)smp[base] + (float)smp[base + 7 * CPH]) * 0.25f;
        if (++rr == 49) { rr = 0; ++cc; }
      }
      __builtin_nontemporal_store(v, dst + idx);
    }
    rem += 39; c += 41;                 // advance by 2048 outputs
    if (rem >= 49) { rem -= 49; ++c; }
  }
}

// ---------------- Host launch ----------------
extern "C" void kernel_launch(void* const* d_in, const int* in_sizes, int n_in,
                              void* d_out, int out_size, void* d_ws, size_t ws_size,
                              hipStream_t stream) {
  (void)n_in; (void)out_size; (void)ws_size;
  const float* features = (const float*)d_in[0];
  const float* rois     = (const float*)d_in[1];
  const int*   bids     = (const int*)d_in[2];
  float* out = (float*)d_out;
  const int R = in_sizes[1] / 4;  // 4000

  _Float16* nhwc  = (_Float16*)d_ws;                    // 31.1 MB (f16 NHWC)
  int*      order = (int*)((char*)d_ws + (64u << 20));  // 16 KB at +64 MB

  bin_rois<<<1, 256, 0, stream>>>(rois, bids, R, order);
  dim3 tgrid((FW + 31) / 32, FH, N_IMG);  // (5, 100, 4)
  transpose_nchw_nhwc<<<tgrid, 256, 0, stream>>>(features, nhwc);
  roialign_nhwc<<<R, 512, 0, stream>>>(nhwc, rois, bids, order, R, out);
}

// Round 17
// 273.102 us; speedup vs baseline: 1.0243x; 1.0243x over previous
//
#include <hip/hip_runtime.h>

#define N_IMG 4
#define C_CH  256
#define FH    100
#define FW    152
#define CHW   (C_CH * FH * FW)
#define OUT_PER_ROI (C_CH * 7 * 7)   // 12544
#define SCALE 0.0625f
#define H_ROW_BYTES (FW * C_CH * 2)  // 77824  (f16 NHWC feature row)
#define H_CH_BYTES  (C_CH * 2)       // 512    (one (y,x) cell, f16)
#define CPH 260                      // f16 LDS row stride (elements) — MUST be >= C_CH=256.
                                     // 520 B rows (8-B aligned); 56*260*2 = 29,120 B LDS.

typedef float    f4 __attribute__((ext_vector_type(4)));
typedef _Float16 h4 __attribute__((ext_vector_type(4)));

// ---------------- Kernel 1 (fused prep): NCHW->NHWC f16 transpose + ROI binning
// grid (5,100,5): z<4 blocks transpose image z; block (0,0,4) does the
// (image, 8x8 cell) counting sort of ROI indices concurrently (independent
// in/out); remaining z==4 blocks exit. Removes the serialized 1-block
// bin_rois dispatch + one launch gap.
__global__ __launch_bounds__(256) void prep_fused(
    const float* __restrict__ in, _Float16* __restrict__ out,
    const float* __restrict__ rois, const int* __restrict__ bids, int R,
    int* __restrict__ order) {
  __shared__ float tile[32][C_CH + 4];   // transpose staging (also covers bin's 2KB)
  if (blockIdx.z == N_IMG) {
    if (blockIdx.x != 0 || blockIdx.y != 0) return;
    __shared__ int hist[256];
    __shared__ int base[256];
    for (int k = threadIdx.x; k < 256; k += 256) hist[k] = 0;
    __syncthreads();
    for (int r = threadIdx.x; r < R; r += 256) {
      const float cx = (rois[r * 4 + 0] + rois[r * 4 + 2]) * 0.5f * SCALE;
      const float cy = (rois[r * 4 + 1] + rois[r * 4 + 3]) * 0.5f * SCALE;
      int xb = (int)(cx * (8.0f / FW)); xb = xb < 0 ? 0 : (xb > 7 ? 7 : xb);
      int yb = (int)(cy * (8.0f / FH)); yb = yb < 0 ? 0 : (yb > 7 ? 7 : yb);
      const int key = (bids[r] << 6) | (yb << 3) | xb;
      atomicAdd(&hist[key], 1);
    }
    __syncthreads();
    if (threadIdx.x == 0) {
      int s = 0;
      for (int k = 0; k < 256; ++k) { base[k] = s; s += hist[k]; }
    }
    __syncthreads();
    for (int r = threadIdx.x; r < R; r += 256) {
      const float cx = (rois[r * 4 + 0] + rois[r * 4 + 2]) * 0.5f * SCALE;
      const float cy = (rois[r * 4 + 1] + rois[r * 4 + 3]) * 0.5f * SCALE;
      int xb = (int)(cx * (8.0f / FW)); xb = xb < 0 ? 0 : (xb > 7 ? 7 : xb);
      int yb = (int)(cy * (8.0f / FH)); yb = yb < 0 ? 0 : (yb > 7 ? 7 : yb);
      const int key = (bids[r] << 6) | (yb << 3) | xb;
      const int pos = atomicAdd(&base[key], 1);
      order[pos] = r;
    }
    return;
  }

  // -------- transpose path (identical to R13) --------
  const int x0 = blockIdx.x * 32;
  const int y  = blockIdx.y;
  const int b  = blockIdx.z;
  const int chl = threadIdx.x & 31;
  const int xq  = threadIdx.x >> 5;
  const int x   = x0 + xq * 4;
  const bool inb = (x < FW);
  const float4* src4 = (const float4*)in;
#pragma unroll
  for (int cc = 0; cc < C_CH; cc += 32) {
    const int ch = cc + chl;
    float4 v = make_float4(0.f, 0.f, 0.f, 0.f);
    if (inb) v = src4[((size_t)b * C_CH + ch) * (FH * FW / 4) + y * (FW / 4) + (x >> 2)];
    tile[xq * 4 + 0][ch] = v.x;
    tile[xq * 4 + 1][ch] = v.y;
    tile[xq * 4 + 2][ch] = v.z;
    tile[xq * 4 + 3][ch] = v.w;
  }
  __syncthreads();
  const int chg = threadIdx.x & 63;
  const int xs  = threadIdx.x >> 6;
  _Float16* dstB = out + (((size_t)b * FH + y) * FW) * C_CH;
#pragma unroll
  for (int xi = 0; xi < 32; xi += 4) {
    const int xx = x0 + xi + xs;
    if (xx < FW) {
      const f4 v = *(const f4*)&tile[xi + xs][chg * 4];
      h4 hv;
      hv[0] = (_Float16)v[0]; hv[1] = (_Float16)v[1];
      hv[2] = (_Float16)v[2]; hv[3] = (_Float16)v[3];
      *(h4*)(dstB + (size_t)xx * C_CH + chg * 4) = hv;
    }
  }
}

// ---------------- Kernel 2: RoIAlign + 2x2 avg pool, f16-hp staged ----------
// 512 threads, one block per ROI. Wave i gathers sample row i (32 h4 loads in
// flight), bilinear in f32, stages HORIZONTAL pair-sums hp[i][j] as f16 in
// LDS [56][CPH] (29.1 KB). Phase 2: out = (hp[rr] + hp[rr+7]) * 0.25.
// __launch_bounds__(512,6): 3 blocks/CU, 24 waves/CU, VGPR cap ~85 —
// measured optimum (R13: 277.3; (512,4)=291, (512,8)=279.7).
__global__ __launch_bounds__(512, 6) void roialign_nhwc(
    const _Float16* __restrict__ feat, const float* __restrict__ rois,
    const int* __restrict__ bids, const int* __restrict__ order,
    int R, float* __restrict__ out) {
  const int g  = blockIdx.x;
  const int r  = order[((R & 7) == 0) ? ((g & 7) * (R >> 3) + (g >> 3)) : g];
  const int cg = threadIdx.x & 63;       // channel group: channels 4*cg..4*cg+3
  const int i  = threadIdx.x >> 6;       // sample row 0..7 (wave-uniform)
  __shared__ _Float16 smp[56 * CPH];     // 29,120 B

  const float x1 = rois[r * 4 + 0] * SCALE;
  const float y1 = rois[r * 4 + 1] * SCALE;
  const float x2 = rois[r * 4 + 2] * SCALE;
  const float y2 = rois[r * 4 + 3] * SCALE;
  const int   b  = bids[r];
  const float bw = fmaxf(x2 - x1 + 1.0f, 0.0f) * (1.0f / 7.0f);
  const float bh = fmaxf(y2 - y1 + 1.0f, 0.0f) * (1.0f / 7.0f);

  // Row weights (wave-uniform).
  const float h   = y1 + (float)i * bh;
  const float hsf = fminf(fmaxf(floorf(h), 0.0f), (float)(FH - 2));
  const float hr  = h - hsf;
  const float mh  = (h >= 0.0f && h < (float)FH) ? 1.0f : 0.0f;
  const float a0  = (1.0f - hr) * mh;
  const float a1  = hr * mh;

  const char* fbb  = (const char*)feat + (size_t)b * CHW * 2;
  const int   row0 = (int)hsf * H_ROW_BYTES + cg * 8;

  _Float16* lbase = &smp[(i * 7) * CPH + cg * 4];   // byte off = i*3640 + cg*8: 8-B aligned

  f4 prev;
#pragma unroll
  for (int j = 0; j < 8; ++j) {
    const float w   = x1 + (float)j * bw;
    const float wsf = fminf(fmaxf(floorf(w), 0.0f), (float)(FW - 2));
    const float wr  = w - wsf;
    const float mw  = (w >= 0.0f && w < (float)FW) ? 1.0f : 0.0f;
    const float q0  = (1.0f - wr) * mw;
    const float q1  = wr * mw;
    const int   o0  = row0 + (int)wsf * H_CH_BYTES;
    const h4 h00 = *(const h4*)(fbb + o0);
    const h4 h01 = *(const h4*)(fbb + o0 + H_CH_BYTES);
    const h4 h10 = *(const h4*)(fbb + o0 + H_ROW_BYTES);
    const h4 h11 = *(const h4*)(fbb + o0 + H_ROW_BYTES + H_CH_BYTES);
    const f4 g00 = __builtin_convertvector(h00, f4);
    const f4 g01 = __builtin_convertvector(h01, f4);
    const f4 g10 = __builtin_convertvector(h10, f4);
    const f4 g11 = __builtin_convertvector(h11, f4);
    const f4 s = (g00 * q0 + g01 * q1) * a0 +
                 (g10 * q0 + g11 * q1) * a1;
    if (j > 0) {
      const f4 hp = prev + s;                       // hp[i][j-1]
      h4 hh;
      hh[0] = (_Float16)hp[0]; hh[1] = (_Float16)hp[1];
      hh[2] = (_Float16)hp[2]; hh[3] = (_Float16)hp[3];
      *(h4*)(lbase + (j - 1) * CPH) = hh;
    }
    prev = s;
  }

  __syncthreads();

  // Phase 2: pooled writeback, output-linear (coalesced float4 NT stores).
  // Output element g = c*49 + rr, rr = p*7 + j; hp pair at LDS rows rr, rr+7.
  f4* dst = (f4*)(out + (size_t)r * OUT_PER_ROI);
  const int g0 = (int)threadIdx.x * 4;
  int c   = (g0 * 669) >> 15;          // exact g/49 for g < 2048
  int rem = g0 - c * 49;
#pragma unroll
  for (int k = 0; k < 7; ++k) {
    const int idx = (int)threadIdx.x + k * 512;
    if (idx < (OUT_PER_ROI / 4)) {
      f4 v;
      int cc = c, rr = rem;
#pragma unroll
      for (int e = 0; e < 4; ++e) {
        const int base = rr * CPH + cc;
        v[e] = ((float)smp[base] + (float)smp[base + 7 * CPH]) * 0.25f;
        if (++rr == 49) { rr = 0; ++cc; }
      }
      __builtin_nontemporal_store(v, dst + idx);
    }
    rem += 39; c += 41;                 // advance by 2048 outputs
    if (rem >= 49) { rem -= 49; ++c; }
  }
}

// ---------------- Host launch ----------------
extern "C" void kernel_launch(void* const* d_in, const int* in_sizes, int n_in,
                              void* d_out, int out_size, void* d_ws, size_t ws_size,
                              hipStream_t stream) {
  (void)n_in; (void)out_size; (void)ws_size;
  const float* features = (const float*)d_in[0];
  const float* rois     = (const float*)d_in[1];
  const int*   bids     = (const int*)d_in[2];
  float* out = (float*)d_out;
  const int R = in_sizes[1] / 4;  // 4000

  _Float16* nhwc  = (_Float16*)d_ws;                    // 31.1 MB (f16 NHWC)
  int*      order = (int*)((char*)d_ws + (64u << 20));  // 16 KB at +64 MB

  dim3 pgrid((FW + 31) / 32, FH, N_IMG + 1);  // (5, 100, 5): transpose + binning
  prep_fused<<<pgrid, 256, 0, stream>>>(features, nhwc, rois, bids, R, order);
  roialign_nhwc<<<R, 512, 0, stream>>>(nhwc, rois, bids, order, R, out);
}